// Round 4
// baseline (463.683 us; speedup 1.0000x reference)
//
#include <hip/hip_runtime.h>
#include <math.h>

// Problem: B=8, N=2048, D=512, K=16
// R4: sims stored as 16-bit sortable keys (fp16+signmap, transposed write);
// k_topk = threshold binary-search + LDS candidate append + 2-lane fp64
// rescore of <=64 candidates + 64-lane bitonic -> exact reference order.

#define NTOK 2048
#define DIM 512

typedef __attribute__((ext_vector_type(8))) __bf16 bf16x8;
typedef __attribute__((ext_vector_type(4))) float f32x4;
typedef __attribute__((ext_vector_type(8))) unsigned short ushort8;

#define GLDS(gp, lp)                                                      \
  __builtin_amdgcn_global_load_lds(                                       \
      (const __attribute__((address_space(1))) void*)(gp),                \
      (__attribute__((address_space(3))) void*)(lp), 16, 0, 0)

__device__ __forceinline__ ushort f2b(float f) {  // RNE fp32->bf16
  unsigned u = __float_as_uint(f);
  return (ushort)((u + 0x7fffu + ((u >> 16) & 1u)) >> 16);
}
__device__ __forceinline__ float b2f(ushort h) {
  return __uint_as_float((unsigned)h << 16);
}
__device__ __forceinline__ ushort f2key(float v) {  // fp16 RNE + order map
  union { _Float16 h; ushort u; } cv;
  cv.h = (_Float16)v;
  ushort hb = cv.u;
  return (hb & 0x8000u) ? (ushort)~hb : (ushort)(hb | 0x8000u);
}

// norm: xnb=bf16(x/|x|), xb=bf16(x), inv64=1/|x|, L=x@aw^T+ab (fp32 logits)
__global__ __launch_bounds__(64) void k_norm(const float* __restrict__ x,
                                             const float* __restrict__ aw,
                                             const float* __restrict__ ab,
                                             ushort* __restrict__ xnb,
                                             ushort* __restrict__ xb,
                                             double* __restrict__ inv64,
                                             float* __restrict__ L) {
  int row = blockIdx.x, lane = threadIdx.x;
  const float* xr = x + (size_t)row * DIM;
  float4 a = *(const float4*)&xr[lane * 8];
  float4 b = *(const float4*)&xr[lane * 8 + 4];

  float s[16];
#pragma unroll
  for (int k = 0; k < 16; ++k) {
    const float4 w0 = *(const float4*)&aw[(size_t)k * DIM + lane * 8];
    const float4 w1 = *(const float4*)&aw[(size_t)k * DIM + lane * 8 + 4];
    s[k] = a.x * w0.x + a.y * w0.y + a.z * w0.z + a.w * w0.w + b.x * w1.x +
           b.y * w1.y + b.z * w1.z + b.w * w1.w;
  }
#pragma unroll
  for (int off = 1; off < 64; off <<= 1)
#pragma unroll
    for (int k = 0; k < 16; ++k) s[k] += __shfl_xor(s[k], off);

  double ss = (double)a.x * a.x + (double)a.y * a.y + (double)a.z * a.z +
              (double)a.w * a.w + (double)b.x * b.x + (double)b.y * b.y +
              (double)b.z * b.z + (double)b.w * b.w;
#pragma unroll
  for (int off = 32; off >= 1; off >>= 1) ss += __shfl_xor(ss, off);
  double inv = 1.0 / sqrt(ss);
  if (lane == 0) {
    inv64[row] = inv;
#pragma unroll
    for (int k = 0; k < 16; ++k) L[(size_t)row * 16 + k] = s[k] + ab[k];
  }
  float f = (float)inv;
  size_t o = (size_t)row * DIM + lane * 8;
  ushort4 r0 = {f2b(a.x), f2b(a.y), f2b(a.z), f2b(a.w)};
  ushort4 r1 = {f2b(b.x), f2b(b.y), f2b(b.z), f2b(b.w)};
  *(ushort4*)&xb[o] = r0;
  *(ushort4*)&xb[o + 4] = r1;
  ushort4 n0 = {f2b(a.x * f), f2b(a.y * f), f2b(a.z * f), f2b(a.w * f)};
  ushort4 n1 = {f2b(b.x * f), f2b(b.y * f), f2b(b.z * f), f2b(b.w * f)};
  *(ushort4*)&xnb[o] = n0;
  *(ushort4*)&xnb[o + 4] = n1;
}

__global__ __launch_bounds__(256) void k_castw(const float* __restrict__ a,
                                               const float* __restrict__ b,
                                               ushort* __restrict__ ab,
                                               ushort* __restrict__ bb) {
  int i = (blockIdx.x * 256 + threadIdx.x) * 4;
  float4 va = *(const float4*)&a[i];
  float4 vb = *(const float4*)&b[i];
  ushort4 oa = {f2b(va.x), f2b(va.y), f2b(va.z), f2b(va.w)};
  ushort4 ob = {f2b(vb.x), f2b(vb.y), f2b(vb.z), f2b(vb.w)};
  *(ushort4*)&ab[i] = oa;
  *(ushort4*)&bb[i] = ob;
}

// shared bf16 MFMA K-loop (B^T): C128x128 += A[rb..][k]*B[cb..][k]
__device__ __forceinline__ void bt_kloop(const ushort* __restrict__ A,
                                         const ushort* __restrict__ B,
                                         ushort* lA, ushort* lB, int rb, int cb,
                                         int tid, f32x4 (&acc)[4][4]) {
  int wv = tid >> 6, ln = tid & 63;
  int wm = wv >> 1, wn = wv & 1;
  int col = ln & 15, quad = ln >> 4;
  for (int kt = 0; kt < DIM; kt += 32) {
#pragma unroll
    for (int j = 0; j < 2; ++j) {
      int c = j * 256 + wv * 64 + ln;
      int r = c >> 2, seg = c & 3;
      GLDS(A + (size_t)(rb + r) * DIM + kt + seg * 8, lA + c * 8);
      GLDS(B + (size_t)(cb + r) * DIM + kt + seg * 8, lB + c * 8);
    }
    __syncthreads();
    bf16x8 af[4], bf[4];
#pragma unroll
    for (int i = 0; i < 4; ++i) {
      af[i] = *(const bf16x8*)&lA[(wm * 64 + i * 16 + col) * 32 + quad * 8];
      bf[i] = *(const bf16x8*)&lB[(wn * 64 + i * 16 + col) * 32 + quad * 8];
    }
#pragma unroll
    for (int i = 0; i < 4; ++i)
#pragma unroll
      for (int j = 0; j < 4; ++j)
        acc[i][j] =
            __builtin_amdgcn_mfma_f32_16x16x32_bf16(af[i], bf[j], acc[i][j], 0, 0, 0);
    __syncthreads();
  }
}

// key matrix (16-bit) = map(fp16(Xn_z @ Xn_z^T)), written transposed
__global__ __launch_bounds__(256) void k_simgemm(const ushort* __restrict__ Xn,
                                                 ushort* __restrict__ Skey) {
  __shared__ ushort lA[128 * 32];
  __shared__ ushort lB[128 * 32];
  int tid = threadIdx.x;
  int z = blockIdx.z;
  const ushort* Xb = Xn + (size_t)z * NTOK * DIM;
  ushort* Sb = Skey + (size_t)z * NTOK * NTOK;
  int rb = blockIdx.x * 128, cb = blockIdx.y * 128;
  f32x4 zero = {0.f, 0.f, 0.f, 0.f};
  f32x4 acc[4][4];
#pragma unroll
  for (int i = 0; i < 4; ++i)
#pragma unroll
    for (int j = 0; j < 4; ++j) acc[i][j] = zero;
  bt_kloop(Xb, Xb, lA, lB, rb, cb, tid, acc);
  int wv = tid >> 6, ln = tid & 63;
  int wm = wv >> 1, wn = wv & 1;
  int col = ln & 15, quad = ln >> 4;
#pragma unroll
  for (int i = 0; i < 4; ++i)
#pragma unroll
    for (int j = 0; j < 4; ++j) {
      int m0 = rb + wm * 64 + i * 16 + quad * 4;  // 4 consecutive sim-rows
      int nn = cb + wn * 64 + j * 16 + col;
      ushort4 kk = {f2key(acc[i][j][0]), f2key(acc[i][j][1]),
                    f2key(acc[i][j][2]), f2key(acc[i][j][3])};
      // transposed write: W symmetric, 8B contiguous store
      *(ushort4*)&Sb[(size_t)nn * NTOK + m0] = kk;
    }
}

// out = relu(Mg@Wm^T) + Xg@Wo^T
__global__ __launch_bounds__(256) void k_proj(const ushort* __restrict__ Mg,
                                              const ushort* __restrict__ Wm,
                                              const ushort* __restrict__ Xg,
                                              const ushort* __restrict__ Wo,
                                              float* __restrict__ out) {
  __shared__ ushort lA[128 * 32];
  __shared__ ushort lB[128 * 32];
  int tid = threadIdx.x;
  int rb = blockIdx.x * 128, cb = blockIdx.y * 128;
  f32x4 zero = {0.f, 0.f, 0.f, 0.f};
  f32x4 a1[4][4], a2[4][4];
#pragma unroll
  for (int i = 0; i < 4; ++i)
#pragma unroll
    for (int j = 0; j < 4; ++j) { a1[i][j] = zero; a2[i][j] = zero; }
  bt_kloop(Mg, Wm, lA, lB, rb, cb, tid, a1);
  bt_kloop(Xg, Wo, lA, lB, rb, cb, tid, a2);
  int wv = tid >> 6, ln = tid & 63;
  int wm = wv >> 1, wn = wv & 1;
  int col = ln & 15, quad = ln >> 4;
#pragma unroll
  for (int i = 0; i < 4; ++i)
#pragma unroll
    for (int j = 0; j < 4; ++j)
#pragma unroll
      for (int r = 0; r < 4; ++r) {
        int m = rb + wm * 64 + i * 16 + quad * 4 + r;
        int n = cb + wn * 64 + j * 16 + col;
        out[(size_t)m * DIM + n] = fmaxf(a1[i][j][r], 0.f) + a2[i][j][r];
      }
}

// 128 threads/row. Wave0: threshold binary-search (count in [32,64]) +
// candidate append. All: 2-lane fp64 rescore. Wave0: 64-lane bitonic ->
// top-16 indices in exact (val desc, idx asc) reference order.
__global__ __launch_bounds__(128) void k_topk(const ushort* __restrict__ simk,
                                              const float* __restrict__ x,
                                              const double* __restrict__ inv64,
                                              int* __restrict__ idx16,
                                              int batch0) {
  int n = blockIdx.x;
  int batch = batch0 + blockIdx.y;
  int t = threadIdx.x;
  __shared__ int lcnt;
  __shared__ int lidx[64];
  __shared__ double pd[128];
  const ushort* srow = simk + ((size_t)blockIdx.y * NTOK + (size_t)n) * NTOK;
  if (t < 64) {
    ushort kv[32];
#pragma unroll
    for (int q = 0; q < 4; ++q) {
      ushort8 v8 = *(const ushort8*)&srow[t * 32 + q * 8];
#pragma unroll
      for (int e = 0; e < 8; ++e) kv[q * 8 + e] = v8[e];
    }
    unsigned thr = 0;
    int cnt = NTOK;
    for (int bit = 15; bit >= 0 && cnt > 64; --bit) {
      unsigned cand = thr | (1u << bit);
      int c2 = 0;
#pragma unroll
      for (int j2 = 0; j2 < 32; ++j2) c2 += (kv[j2] >= cand) ? 1 : 0;
#pragma unroll
      for (int off = 1; off < 64; off <<= 1) c2 += __shfl_xor(c2, off);
      if (c2 >= 32) { thr = cand; cnt = c2; }
    }
    if (t == 0) lcnt = 0;
#pragma unroll
    for (int j2 = 0; j2 < 32; ++j2) {
      if ((unsigned)kv[j2] >= thr) {
        int slot = atomicAdd(&lcnt, 1);
        if (slot < 64) lidx[slot] = t * 32 + j2;
      }
    }
  }
  __syncthreads();
  int c = lcnt < 64 ? lcnt : 64;
  int j = t & 63, h = t >> 6;
  int m = (j < c) ? lidx[j] : n;
  const float* xa = x + ((size_t)batch * NTOK + n) * DIM + h * 256;
  const float* xc = x + ((size_t)batch * NTOK + m) * DIM + h * 256;
  double s = 0.0;
#pragma unroll 4
  for (int q = 0; q < 256; q += 4) {
    float4 a = *(const float4*)&xa[q];
    float4 b = *(const float4*)&xc[q];
    s = fma((double)a.x, (double)b.x, s);
    s = fma((double)a.y, (double)b.y, s);
    s = fma((double)a.z, (double)b.z, s);
    s = fma((double)a.w, (double)b.w, s);
  }
  pd[t] = s;
  __syncthreads();
  if (t < 64) {
    double val = (pd[t] + pd[t + 64]) * inv64[(size_t)batch * NTOK + n] *
                 inv64[(size_t)batch * NTOK + m];
    double sv = (t < c) ? val : -1.0e300;
    int si = (t < c) ? m : 0x7FFFFFFF;
#pragma unroll
    for (int k = 2; k <= 64; k <<= 1) {
#pragma unroll
      for (int jj = k >> 1; jj > 0; jj >>= 1) {
        double ov = __shfl_xor(sv, jj);
        int oi = __shfl_xor(si, jj);
        bool lower = (t & jj) == 0;
        bool desc = (t & k) == 0;
        bool takeFirst = (lower == desc);
        bool otherFirst = (ov > sv) || (ov == sv && oi < si);
        if (takeFirst == otherFirst) { sv = ov; si = oi; }
      }
    }
    if (t < 16) idx16[((size_t)batch * NTOK + n) * 16 + t] = si;
  }
}

// one block per row: mutual check + 16-wide softmax (wave 0), then weighted
// aggregation of bf16 neighbor rows -> bf16 merged.
__global__ __launch_bounds__(128) void k_merge(const ushort* __restrict__ xb,
                                               const int* __restrict__ idx16,
                                               const float* __restrict__ L,
                                               ushort* __restrict__ mergedb) {
  int row = blockIdx.x;
  int b = row >> 11, n = row & (NTOK - 1);
  int t = threadIdx.x;
  __shared__ float ps[16];
  __shared__ int ms[16];
  if (t < 64) {
    int k = t & 15;
    int m = idx16[(size_t)row * 16 + k];
    const int* mrow = idx16 + (size_t)(b * NTOK + m) * 16;
    int4 q0 = *(const int4*)&mrow[0];
    int4 q1 = *(const int4*)&mrow[4];
    int4 q2 = *(const int4*)&mrow[8];
    int4 q3 = *(const int4*)&mrow[12];
    bool mut = (q0.x == n) | (q0.y == n) | (q0.z == n) | (q0.w == n) |
               (q1.x == n) | (q1.y == n) | (q1.z == n) | (q1.w == n) |
               (q2.x == n) | (q2.y == n) | (q2.z == n) | (q2.w == n) |
               (q3.x == n) | (q3.y == n) | (q3.z == n) | (q3.w == n);
    float l = mut ? L[(size_t)row * 16 + k] : -__builtin_inff();
    float mx = l;
#pragma unroll
    for (int off = 1; off < 16; off <<= 1) mx = fmaxf(mx, __shfl_xor(mx, off));
    float e = mut ? __expf(l - mx) : 0.0f;
    float den = e;
#pragma unroll
    for (int off = 1; off < 16; off <<= 1) den += __shfl_xor(den, off);
    if (t < 16) { ps[t] = e / den; ms[t] = m; }
  }
  __syncthreads();
  float4 acc = {0.f, 0.f, 0.f, 0.f};
#pragma unroll
  for (int k = 0; k < 16; ++k) {
    float pk = ps[k];
    if (pk != 0.0f) {  // uniform across block
      ushort4 v = *(const ushort4*)&xb[(size_t)(b * NTOK + ms[k]) * DIM + t * 4];
      acc.x = fmaf(pk, b2f(v.x), acc.x);
      acc.y = fmaf(pk, b2f(v.y), acc.y);
      acc.z = fmaf(pk, b2f(v.z), acc.z);
      acc.w = fmaf(pk, b2f(v.w), acc.w);
    }
  }
  ushort4 o = {f2b(acc.x), f2b(acc.y), f2b(acc.z), f2b(acc.w)};
  *(ushort4*)&mergedb[(size_t)row * DIM + t * 4] = o;
}

extern "C" void kernel_launch(void* const* d_in, const int* in_sizes, int n_in,
                              void* d_out, int out_size, void* d_ws,
                              size_t ws_size, hipStream_t stream) {
  const float* x = (const float*)d_in[0];
  const float* attn_w = (const float*)d_in[1];
  const float* attn_b = (const float*)d_in[2];
  const float* w_merged = (const float*)d_in[3];
  const float* w_orig = (const float*)d_in[4];
  float* out = (float*)d_out;

  char* w = (char*)d_ws;
  ushort* xnb = (ushort*)(w);                 // 16,777,216
  ushort* xb = (ushort*)(w + 16777216);       // 16,777,216
  double* inv64 = (double*)(w + 33554432);    //    131,072
  ushort* wmb = (ushort*)(w + 33685504);      //    524,288
  ushort* wob = (ushort*)(w + 34209792);      //    524,288
  int* idx16 = (int*)(w + 34734080);          //  1,048,576
  float* L = (float*)(w + 35782656);          //  1,048,576 (logits)
  ushort* simk = (ushort*)(w + 36831232);     //  pb x 8,388,608 (16-bit keys)
  ushort* mergedb = (ushort*)(w + 36831232);  // alias: simk dead after topk

  size_t fixed = 36831232ull, per = 8388608ull;
  int pb = 1;
  if (ws_size >= fixed + 8 * per) pb = 8;
  else if (ws_size >= fixed + 4 * per) pb = 4;
  else if (ws_size >= fixed + 2 * per) pb = 2;

  k_norm<<<16384, 64, 0, stream>>>(x, attn_w, attn_b, xnb, xb, inv64, L);
  k_castw<<<256, 256, 0, stream>>>(w_merged, w_orig, wmb, wob);
  for (int b = 0; b < 8; b += pb) {
    k_simgemm<<<dim3(16, 16, pb), 256, 0, stream>>>(
        xnb + (size_t)b * NTOK * DIM, simk);
    k_topk<<<dim3(NTOK, pb), 128, 0, stream>>>(simk, x, inv64, idx16, b);
  }
  k_merge<<<16384, 128, 0, stream>>>(xb, idx16, L, mergedb);
  k_proj<<<dim3(128, 4), 256, 0, stream>>>(mergedb, wmb, xb, wob, out);
}

// Round 6
// 456.536 us; speedup vs baseline: 1.0157x; 1.0157x over previous
//
#include <hip/hip_runtime.h>
#include <math.h>

// Problem: B=8, N=2048, D=512, K=16
// R6 = R4 selection window [32,64] (proven safe: 16-rank margin ~1.6e-2 vs
// ~1e-4 approx noise) + R5 XCD-partitioned flat grids for the gather kernels
// (batch = blockIdx.x & 7 -> each per-XCD L2 caches one 4MB x-slice).

#define NTOK 2048
#define DIM 512

typedef __attribute__((ext_vector_type(8))) __bf16 bf16x8;
typedef __attribute__((ext_vector_type(4))) float f32x4;
typedef __attribute__((ext_vector_type(8))) unsigned short ushort8;

#define GLDS(gp, lp)                                                      \
  __builtin_amdgcn_global_load_lds(                                       \
      (const __attribute__((address_space(1))) void*)(gp),                \
      (__attribute__((address_space(3))) void*)(lp), 16, 0, 0)

__device__ __forceinline__ ushort f2b(float f) {  // RNE fp32->bf16
  unsigned u = __float_as_uint(f);
  return (ushort)((u + 0x7fffu + ((u >> 16) & 1u)) >> 16);
}
__device__ __forceinline__ float b2f(ushort h) {
  return __uint_as_float((unsigned)h << 16);
}
__device__ __forceinline__ ushort f2key(float v) {  // fp16 RNE + order map
  union { _Float16 h; ushort u; } cv;
  cv.h = (_Float16)v;
  ushort hb = cv.u;
  return (hb & 0x8000u) ? (ushort)~hb : (ushort)(hb | 0x8000u);
}

// norm: xnb=bf16(x/|x|), xb=bf16(x), inv64=1/|x|, L=x@aw^T+ab (fp32 logits)
__global__ __launch_bounds__(64) void k_norm(const float* __restrict__ x,
                                             const float* __restrict__ aw,
                                             const float* __restrict__ ab,
                                             ushort* __restrict__ xnb,
                                             ushort* __restrict__ xb,
                                             double* __restrict__ inv64,
                                             float* __restrict__ L) {
  int row = blockIdx.x, lane = threadIdx.x;
  const float* xr = x + (size_t)row * DIM;
  float4 a = *(const float4*)&xr[lane * 8];
  float4 b = *(const float4*)&xr[lane * 8 + 4];

  float s[16];
#pragma unroll
  for (int k = 0; k < 16; ++k) {
    const float4 w0 = *(const float4*)&aw[(size_t)k * DIM + lane * 8];
    const float4 w1 = *(const float4*)&aw[(size_t)k * DIM + lane * 8 + 4];
    s[k] = a.x * w0.x + a.y * w0.y + a.z * w0.z + a.w * w0.w + b.x * w1.x +
           b.y * w1.y + b.z * w1.z + b.w * w1.w;
  }
#pragma unroll
  for (int off = 1; off < 64; off <<= 1)
#pragma unroll
    for (int k = 0; k < 16; ++k) s[k] += __shfl_xor(s[k], off);

  double ss = (double)a.x * a.x + (double)a.y * a.y + (double)a.z * a.z +
              (double)a.w * a.w + (double)b.x * b.x + (double)b.y * b.y +
              (double)b.z * b.z + (double)b.w * b.w;
#pragma unroll
  for (int off = 32; off >= 1; off >>= 1) ss += __shfl_xor(ss, off);
  double inv = 1.0 / sqrt(ss);
  if (lane == 0) {
    inv64[row] = inv;
#pragma unroll
    for (int k = 0; k < 16; ++k) L[(size_t)row * 16 + k] = s[k] + ab[k];
  }
  float f = (float)inv;
  size_t o = (size_t)row * DIM + lane * 8;
  ushort4 r0 = {f2b(a.x), f2b(a.y), f2b(a.z), f2b(a.w)};
  ushort4 r1 = {f2b(b.x), f2b(b.y), f2b(b.z), f2b(b.w)};
  *(ushort4*)&xb[o] = r0;
  *(ushort4*)&xb[o + 4] = r1;
  ushort4 n0 = {f2b(a.x * f), f2b(a.y * f), f2b(a.z * f), f2b(a.w * f)};
  ushort4 n1 = {f2b(b.x * f), f2b(b.y * f), f2b(b.z * f), f2b(b.w * f)};
  *(ushort4*)&xnb[o] = n0;
  *(ushort4*)&xnb[o + 4] = n1;
}

__global__ __launch_bounds__(256) void k_castw(const float* __restrict__ a,
                                               const float* __restrict__ b,
                                               ushort* __restrict__ ab,
                                               ushort* __restrict__ bb) {
  int i = (blockIdx.x * 256 + threadIdx.x) * 4;
  float4 va = *(const float4*)&a[i];
  float4 vb = *(const float4*)&b[i];
  ushort4 oa = {f2b(va.x), f2b(va.y), f2b(va.z), f2b(va.w)};
  ushort4 ob = {f2b(vb.x), f2b(vb.y), f2b(vb.z), f2b(vb.w)};
  *(ushort4*)&ab[i] = oa;
  *(ushort4*)&bb[i] = ob;
}

// shared bf16 MFMA K-loop (B^T): C128x128 += A[rb..][k]*B[cb..][k]
__device__ __forceinline__ void bt_kloop(const ushort* __restrict__ A,
                                         const ushort* __restrict__ B,
                                         ushort* lA, ushort* lB, int rb, int cb,
                                         int tid, f32x4 (&acc)[4][4]) {
  int wv = tid >> 6, ln = tid & 63;
  int wm = wv >> 1, wn = wv & 1;
  int col = ln & 15, quad = ln >> 4;
  for (int kt = 0; kt < DIM; kt += 32) {
#pragma unroll
    for (int j = 0; j < 2; ++j) {
      int c = j * 256 + wv * 64 + ln;
      int r = c >> 2, seg = c & 3;
      GLDS(A + (size_t)(rb + r) * DIM + kt + seg * 8, lA + c * 8);
      GLDS(B + (size_t)(cb + r) * DIM + kt + seg * 8, lB + c * 8);
    }
    __syncthreads();
    bf16x8 af[4], bf[4];
#pragma unroll
    for (int i = 0; i < 4; ++i) {
      af[i] = *(const bf16x8*)&lA[(wm * 64 + i * 16 + col) * 32 + quad * 8];
      bf[i] = *(const bf16x8*)&lB[(wn * 64 + i * 16 + col) * 32 + quad * 8];
    }
#pragma unroll
    for (int i = 0; i < 4; ++i)
#pragma unroll
      for (int j = 0; j < 4; ++j)
        acc[i][j] =
            __builtin_amdgcn_mfma_f32_16x16x32_bf16(af[i], bf[j], acc[i][j], 0, 0, 0);
    __syncthreads();
  }
}

// key matrix (16-bit) = map(fp16(Xn_z @ Xn_z^T)), written transposed
__global__ __launch_bounds__(256) void k_simgemm(const ushort* __restrict__ Xn,
                                                 ushort* __restrict__ Skey) {
  __shared__ ushort lA[128 * 32];
  __shared__ ushort lB[128 * 32];
  int tid = threadIdx.x;
  int z = blockIdx.z;
  const ushort* Xb = Xn + (size_t)z * NTOK * DIM;
  ushort* Sb = Skey + (size_t)z * NTOK * NTOK;
  int rb = blockIdx.x * 128, cb = blockIdx.y * 128;
  f32x4 zero = {0.f, 0.f, 0.f, 0.f};
  f32x4 acc[4][4];
#pragma unroll
  for (int i = 0; i < 4; ++i)
#pragma unroll
    for (int j = 0; j < 4; ++j) acc[i][j] = zero;
  bt_kloop(Xb, Xb, lA, lB, rb, cb, tid, acc);
  int wv = tid >> 6, ln = tid & 63;
  int wm = wv >> 1, wn = wv & 1;
  int col = ln & 15, quad = ln >> 4;
#pragma unroll
  for (int i = 0; i < 4; ++i)
#pragma unroll
    for (int j = 0; j < 4; ++j) {
      int m0 = rb + wm * 64 + i * 16 + quad * 4;
      int nn = cb + wn * 64 + j * 16 + col;
      ushort4 kk = {f2key(acc[i][j][0]), f2key(acc[i][j][1]),
                    f2key(acc[i][j][2]), f2key(acc[i][j][3])};
      *(ushort4*)&Sb[(size_t)nn * NTOK + m0] = kk;  // W symmetric
    }
}

// out = relu(Mg@Wm^T) + Xg@Wo^T
__global__ __launch_bounds__(256) void k_proj(const ushort* __restrict__ Mg,
                                              const ushort* __restrict__ Wm,
                                              const ushort* __restrict__ Xg,
                                              const ushort* __restrict__ Wo,
                                              float* __restrict__ out) {
  __shared__ ushort lA[128 * 32];
  __shared__ ushort lB[128 * 32];
  int tid = threadIdx.x;
  int rb = blockIdx.x * 128, cb = blockIdx.y * 128;
  f32x4 zero = {0.f, 0.f, 0.f, 0.f};
  f32x4 a1[4][4], a2[4][4];
#pragma unroll
  for (int i = 0; i < 4; ++i)
#pragma unroll
    for (int j = 0; j < 4; ++j) { a1[i][j] = zero; a2[i][j] = zero; }
  bt_kloop(Mg, Wm, lA, lB, rb, cb, tid, a1);
  bt_kloop(Xg, Wo, lA, lB, rb, cb, tid, a2);
  int wv = tid >> 6, ln = tid & 63;
  int wm = wv >> 1, wn = wv & 1;
  int col = ln & 15, quad = ln >> 4;
#pragma unroll
  for (int i = 0; i < 4; ++i)
#pragma unroll
    for (int j = 0; j < 4; ++j)
#pragma unroll
      for (int r = 0; r < 4; ++r) {
        int m = rb + wm * 64 + i * 16 + quad * 4 + r;
        int n = cb + wn * 64 + j * 16 + col;
        out[(size_t)m * DIM + n] = fmaxf(a1[i][j][r], 0.f) + a2[i][j][r];
      }
}

// 128 thr/row, flat grid: zi = blk & (pb-1) -> XCD-partitioned batches.
// Wave0: threshold search (count in [32,64]) + append. All: 2-thread fp64
// rescore of 64 slots. Wave0: 64-lane bitonic -> top-16 in reference order.
__global__ __launch_bounds__(128) void k_topk(const ushort* __restrict__ simk,
                                              const float* __restrict__ x,
                                              const double* __restrict__ inv64,
                                              int* __restrict__ idx16,
                                              int batch0, int pbm1, int pbsh) {
  int zi = blockIdx.x & pbm1;
  int n = blockIdx.x >> pbsh;
  int batch = batch0 + zi;
  int t = threadIdx.x;
  __shared__ int lcnt;
  __shared__ int lidx[64];
  __shared__ double pd[128];
  const ushort* srow = simk + ((size_t)zi * NTOK + (size_t)n) * NTOK;
  if (t < 64) {
    ushort kv[32];
#pragma unroll
    for (int q = 0; q < 4; ++q) {
      ushort8 v8 = *(const ushort8*)&srow[t * 32 + q * 8];
#pragma unroll
      for (int e = 0; e < 8; ++e) kv[q * 8 + e] = v8[e];
    }
    unsigned thr = 0;
    int cnt = NTOK;
    for (int bit = 15; bit >= 0 && cnt > 64; --bit) {
      unsigned cand = thr | (1u << bit);
      int c2 = 0;
#pragma unroll
      for (int j2 = 0; j2 < 32; ++j2) c2 += (kv[j2] >= cand) ? 1 : 0;
#pragma unroll
      for (int off = 1; off < 64; off <<= 1) c2 += __shfl_xor(c2, off);
      if (c2 >= 32) { thr = cand; cnt = c2; }
    }
    if (t == 0) lcnt = 0;
#pragma unroll
    for (int j2 = 0; j2 < 32; ++j2) {
      if ((unsigned)kv[j2] >= thr) {
        int slot = atomicAdd(&lcnt, 1);
        if (slot < 64) lidx[slot] = t * 32 + j2;
      }
    }
  }
  __syncthreads();
  int c = lcnt < 64 ? lcnt : 64;
  int j = t & 63, h = t >> 6;  // 2 threads per candidate, 256 floats each
  int m = (j < c) ? lidx[j] : n;
  const float* xa = x + ((size_t)batch * NTOK + n) * DIM + h * 256;
  const float* xc = x + ((size_t)batch * NTOK + m) * DIM + h * 256;
  double s = 0.0;
#pragma unroll 4
  for (int q = 0; q < 256; q += 4) {
    float4 a = *(const float4*)&xa[q];
    float4 b = *(const float4*)&xc[q];
    s = fma((double)a.x, (double)b.x, s);
    s = fma((double)a.y, (double)b.y, s);
    s = fma((double)a.z, (double)b.z, s);
    s = fma((double)a.w, (double)b.w, s);
  }
  pd[t] = s;
  __syncthreads();
  if (t < 64) {
    double val = (pd[t] + pd[t + 64]) * inv64[(size_t)batch * NTOK + n] *
                 inv64[(size_t)batch * NTOK + m];
    double sv = (t < c) ? val : -1.0e300;
    int si = (t < c) ? m : 0x7FFFFFFF;
#pragma unroll
    for (int k = 2; k <= 64; k <<= 1) {
#pragma unroll
      for (int jj = k >> 1; jj > 0; jj >>= 1) {
        double ov = __shfl_xor(sv, jj);
        int oi = __shfl_xor(si, jj);
        bool lower = (t & jj) == 0;
        bool desc = (t & k) == 0;
        bool takeFirst = (lower == desc);
        bool otherFirst = (ov > sv) || (ov == sv && oi < si);
        if (takeFirst == otherFirst) { sv = ov; si = oi; }
      }
    }
    if (t < 16) idx16[((size_t)batch * NTOK + n) * 16 + t] = si;
  }
}

// flat grid, batch = blk & 7 (XCD-partitioned). Wave0: mutual + softmax;
// all 128: weighted aggregation of bf16 neighbor rows -> bf16 merged.
__global__ __launch_bounds__(128) void k_merge(const ushort* __restrict__ xb,
                                               const int* __restrict__ idx16,
                                               const float* __restrict__ L,
                                               ushort* __restrict__ mergedb) {
  int b = blockIdx.x & 7;
  int n = blockIdx.x >> 3;
  int row = (b << 11) | n;
  int t = threadIdx.x;
  __shared__ float ps[16];
  __shared__ int ms[16];
  if (t < 64) {
    int k = t & 15;
    int m = idx16[(size_t)row * 16 + k];
    const int* mrow = idx16 + (size_t)(b * NTOK + m) * 16;
    int4 q0 = *(const int4*)&mrow[0];
    int4 q1 = *(const int4*)&mrow[4];
    int4 q2 = *(const int4*)&mrow[8];
    int4 q3 = *(const int4*)&mrow[12];
    bool mut = (q0.x == n) | (q0.y == n) | (q0.z == n) | (q0.w == n) |
               (q1.x == n) | (q1.y == n) | (q1.z == n) | (q1.w == n) |
               (q2.x == n) | (q2.y == n) | (q2.z == n) | (q2.w == n) |
               (q3.x == n) | (q3.y == n) | (q3.z == n) | (q3.w == n);
    float l = mut ? L[(size_t)row * 16 + k] : -__builtin_inff();
    float mx = l;
#pragma unroll
    for (int off = 1; off < 16; off <<= 1) mx = fmaxf(mx, __shfl_xor(mx, off));
    float e = mut ? __expf(l - mx) : 0.0f;
    float den = e;
#pragma unroll
    for (int off = 1; off < 16; off <<= 1) den += __shfl_xor(den, off);
    if (t < 16) { ps[t] = e / den; ms[t] = m; }
  }
  __syncthreads();
  float4 acc = {0.f, 0.f, 0.f, 0.f};
#pragma unroll
  for (int k = 0; k < 16; ++k) {
    float pk = ps[k];
    if (pk != 0.0f) {  // uniform across block
      ushort4 v = *(const ushort4*)&xb[(size_t)(b * NTOK + ms[k]) * DIM + t * 4];
      acc.x = fmaf(pk, b2f(v.x), acc.x);
      acc.y = fmaf(pk, b2f(v.y), acc.y);
      acc.z = fmaf(pk, b2f(v.z), acc.z);
      acc.w = fmaf(pk, b2f(v.w), acc.w);
    }
  }
  ushort4 o = {f2b(acc.x), f2b(acc.y), f2b(acc.z), f2b(acc.w)};
  *(ushort4*)&mergedb[(size_t)row * DIM + t * 4] = o;
}

extern "C" void kernel_launch(void* const* d_in, const int* in_sizes, int n_in,
                              void* d_out, int out_size, void* d_ws,
                              size_t ws_size, hipStream_t stream) {
  const float* x = (const float*)d_in[0];
  const float* attn_w = (const float*)d_in[1];
  const float* attn_b = (const float*)d_in[2];
  const float* w_merged = (const float*)d_in[3];
  const float* w_orig = (const float*)d_in[4];
  float* out = (float*)d_out;

  char* w = (char*)d_ws;
  ushort* xnb = (ushort*)(w);                 // 16,777,216
  ushort* xb = (ushort*)(w + 16777216);       // 16,777,216
  double* inv64 = (double*)(w + 33554432);    //    131,072
  ushort* wmb = (ushort*)(w + 33685504);      //    524,288
  ushort* wob = (ushort*)(w + 34209792);      //    524,288
  int* idx16 = (int*)(w + 34734080);          //  1,048,576
  float* L = (float*)(w + 35782656);          //  1,048,576 (logits)
  ushort* simk = (ushort*)(w + 36831232);     //  pb x 8,388,608 (16-bit keys)
  ushort* mergedb = (ushort*)(w + 36831232);  // alias: simk dead after topk

  size_t fixed = 36831232ull, per = 8388608ull;
  int pb = 1, pbsh = 0;
  if (ws_size >= fixed + 8 * per) { pb = 8; pbsh = 3; }
  else if (ws_size >= fixed + 4 * per) { pb = 4; pbsh = 2; }
  else if (ws_size >= fixed + 2 * per) { pb = 2; pbsh = 1; }

  k_norm<<<16384, 64, 0, stream>>>(x, attn_w, attn_b, xnb, xb, inv64, L);
  k_castw<<<256, 256, 0, stream>>>(w_merged, w_orig, wmb, wob);
  for (int b = 0; b < 8; b += pb) {
    k_simgemm<<<dim3(16, 16, pb), 256, 0, stream>>>(
        xnb + (size_t)b * NTOK * DIM, simk);
    k_topk<<<NTOK * pb, 128, 0, stream>>>(simk, x, inv64, idx16, b, pb - 1,
                                          pbsh);
  }
  k_merge<<<16384, 128, 0, stream>>>(xb, idx16, L, mergedb);
  k_proj<<<dim3(128, 4), 256, 0, stream>>>(mergedb, wmb, xb, wob, out);
}

// Round 7
// 358.039 us; speedup vs baseline: 1.2951x; 1.2751x over previous
//
#include <hip/hip_runtime.h>
#include <math.h>

// Problem: B=8, N=2048, D=512, K=16
// R7: k_topk restructured around the gather. 256 thr/row: wave0 does the
// [24,48] threshold search; then each wave rescores candidates with
// COALESCED row loads (64 lanes on one candidate row, 16 lines/inst vs 64
// scattered in R6) + fp64 butterfly; wave0 bitonic -> exact reference order.

#define NTOK 2048
#define DIM 512

typedef __attribute__((ext_vector_type(8))) __bf16 bf16x8;
typedef __attribute__((ext_vector_type(4))) float f32x4;
typedef __attribute__((ext_vector_type(8))) unsigned short ushort8;

#define GLDS(gp, lp)                                                      \
  __builtin_amdgcn_global_load_lds(                                       \
      (const __attribute__((address_space(1))) void*)(gp),                \
      (__attribute__((address_space(3))) void*)(lp), 16, 0, 0)

__device__ __forceinline__ ushort f2b(float f) {  // RNE fp32->bf16
  unsigned u = __float_as_uint(f);
  return (ushort)((u + 0x7fffu + ((u >> 16) & 1u)) >> 16);
}
__device__ __forceinline__ float b2f(ushort h) {
  return __uint_as_float((unsigned)h << 16);
}
__device__ __forceinline__ ushort f2key(float v) {  // fp16 RNE + order map
  union { _Float16 h; ushort u; } cv;
  cv.h = (_Float16)v;
  ushort hb = cv.u;
  return (hb & 0x8000u) ? (ushort)~hb : (ushort)(hb | 0x8000u);
}

// norm: xnb=bf16(x/|x|), xb=bf16(x), inv64=1/|x|, L=x@aw^T+ab (fp32 logits)
__global__ __launch_bounds__(64) void k_norm(const float* __restrict__ x,
                                             const float* __restrict__ aw,
                                             const float* __restrict__ ab,
                                             ushort* __restrict__ xnb,
                                             ushort* __restrict__ xb,
                                             double* __restrict__ inv64,
                                             float* __restrict__ L) {
  int row = blockIdx.x, lane = threadIdx.x;
  const float* xr = x + (size_t)row * DIM;
  float4 a = *(const float4*)&xr[lane * 8];
  float4 b = *(const float4*)&xr[lane * 8 + 4];

  float s[16];
#pragma unroll
  for (int k = 0; k < 16; ++k) {
    const float4 w0 = *(const float4*)&aw[(size_t)k * DIM + lane * 8];
    const float4 w1 = *(const float4*)&aw[(size_t)k * DIM + lane * 8 + 4];
    s[k] = a.x * w0.x + a.y * w0.y + a.z * w0.z + a.w * w0.w + b.x * w1.x +
           b.y * w1.y + b.z * w1.z + b.w * w1.w;
  }
#pragma unroll
  for (int off = 1; off < 64; off <<= 1)
#pragma unroll
    for (int k = 0; k < 16; ++k) s[k] += __shfl_xor(s[k], off);

  double ss = (double)a.x * a.x + (double)a.y * a.y + (double)a.z * a.z +
              (double)a.w * a.w + (double)b.x * b.x + (double)b.y * b.y +
              (double)b.z * b.z + (double)b.w * b.w;
#pragma unroll
  for (int off = 32; off >= 1; off >>= 1) ss += __shfl_xor(ss, off);
  double inv = 1.0 / sqrt(ss);
  if (lane == 0) {
    inv64[row] = inv;
#pragma unroll
    for (int k = 0; k < 16; ++k) L[(size_t)row * 16 + k] = s[k] + ab[k];
  }
  float f = (float)inv;
  size_t o = (size_t)row * DIM + lane * 8;
  ushort4 r0 = {f2b(a.x), f2b(a.y), f2b(a.z), f2b(a.w)};
  ushort4 r1 = {f2b(b.x), f2b(b.y), f2b(b.z), f2b(b.w)};
  *(ushort4*)&xb[o] = r0;
  *(ushort4*)&xb[o + 4] = r1;
  ushort4 n0 = {f2b(a.x * f), f2b(a.y * f), f2b(a.z * f), f2b(a.w * f)};
  ushort4 n1 = {f2b(b.x * f), f2b(b.y * f), f2b(b.z * f), f2b(b.w * f)};
  *(ushort4*)&xnb[o] = n0;
  *(ushort4*)&xnb[o + 4] = n1;
}

__global__ __launch_bounds__(256) void k_castw(const float* __restrict__ a,
                                               const float* __restrict__ b,
                                               ushort* __restrict__ ab,
                                               ushort* __restrict__ bb) {
  int i = (blockIdx.x * 256 + threadIdx.x) * 4;
  float4 va = *(const float4*)&a[i];
  float4 vb = *(const float4*)&b[i];
  ushort4 oa = {f2b(va.x), f2b(va.y), f2b(va.z), f2b(va.w)};
  ushort4 ob = {f2b(vb.x), f2b(vb.y), f2b(vb.z), f2b(vb.w)};
  *(ushort4*)&ab[i] = oa;
  *(ushort4*)&bb[i] = ob;
}

// shared bf16 MFMA K-loop (B^T): C128x128 += A[rb..][k]*B[cb..][k]
__device__ __forceinline__ void bt_kloop(const ushort* __restrict__ A,
                                         const ushort* __restrict__ B,
                                         ushort* lA, ushort* lB, int rb, int cb,
                                         int tid, f32x4 (&acc)[4][4]) {
  int wv = tid >> 6, ln = tid & 63;
  int wm = wv >> 1, wn = wv & 1;
  int col = ln & 15, quad = ln >> 4;
  for (int kt = 0; kt < DIM; kt += 32) {
#pragma unroll
    for (int j = 0; j < 2; ++j) {
      int c = j * 256 + wv * 64 + ln;
      int r = c >> 2, seg = c & 3;
      GLDS(A + (size_t)(rb + r) * DIM + kt + seg * 8, lA + c * 8);
      GLDS(B + (size_t)(cb + r) * DIM + kt + seg * 8, lB + c * 8);
    }
    __syncthreads();
    bf16x8 af[4], bf[4];
#pragma unroll
    for (int i = 0; i < 4; ++i) {
      af[i] = *(const bf16x8*)&lA[(wm * 64 + i * 16 + col) * 32 + quad * 8];
      bf[i] = *(const bf16x8*)&lB[(wn * 64 + i * 16 + col) * 32 + quad * 8];
    }
#pragma unroll
    for (int i = 0; i < 4; ++i)
#pragma unroll
      for (int j = 0; j < 4; ++j)
        acc[i][j] =
            __builtin_amdgcn_mfma_f32_16x16x32_bf16(af[i], bf[j], acc[i][j], 0, 0, 0);
    __syncthreads();
  }
}

// key matrix (16-bit) = map(fp16(Xn_z @ Xn_z^T)), written transposed
__global__ __launch_bounds__(256) void k_simgemm(const ushort* __restrict__ Xn,
                                                 ushort* __restrict__ Skey) {
  __shared__ ushort lA[128 * 32];
  __shared__ ushort lB[128 * 32];
  int tid = threadIdx.x;
  int z = blockIdx.z;
  const ushort* Xb = Xn + (size_t)z * NTOK * DIM;
  ushort* Sb = Skey + (size_t)z * NTOK * NTOK;
  int rb = blockIdx.x * 128, cb = blockIdx.y * 128;
  f32x4 zero = {0.f, 0.f, 0.f, 0.f};
  f32x4 acc[4][4];
#pragma unroll
  for (int i = 0; i < 4; ++i)
#pragma unroll
    for (int j = 0; j < 4; ++j) acc[i][j] = zero;
  bt_kloop(Xb, Xb, lA, lB, rb, cb, tid, acc);
  int wv = tid >> 6, ln = tid & 63;
  int wm = wv >> 1, wn = wv & 1;
  int col = ln & 15, quad = ln >> 4;
#pragma unroll
  for (int i = 0; i < 4; ++i)
#pragma unroll
    for (int j = 0; j < 4; ++j) {
      int m0 = rb + wm * 64 + i * 16 + quad * 4;
      int nn = cb + wn * 64 + j * 16 + col;
      ushort4 kk = {f2key(acc[i][j][0]), f2key(acc[i][j][1]),
                    f2key(acc[i][j][2]), f2key(acc[i][j][3])};
      *(ushort4*)&Sb[(size_t)nn * NTOK + m0] = kk;  // W symmetric
    }
}

// out = relu(Mg@Wm^T) + Xg@Wo^T
__global__ __launch_bounds__(256) void k_proj(const ushort* __restrict__ Mg,
                                              const ushort* __restrict__ Wm,
                                              const ushort* __restrict__ Xg,
                                              const ushort* __restrict__ Wo,
                                              float* __restrict__ out) {
  __shared__ ushort lA[128 * 32];
  __shared__ ushort lB[128 * 32];
  int tid = threadIdx.x;
  int rb = blockIdx.x * 128, cb = blockIdx.y * 128;
  f32x4 zero = {0.f, 0.f, 0.f, 0.f};
  f32x4 a1[4][4], a2[4][4];
#pragma unroll
  for (int i = 0; i < 4; ++i)
#pragma unroll
    for (int j = 0; j < 4; ++j) { a1[i][j] = zero; a2[i][j] = zero; }
  bt_kloop(Mg, Wm, lA, lB, rb, cb, tid, a1);
  bt_kloop(Xg, Wo, lA, lB, rb, cb, tid, a2);
  int wv = tid >> 6, ln = tid & 63;
  int wm = wv >> 1, wn = wv & 1;
  int col = ln & 15, quad = ln >> 4;
#pragma unroll
  for (int i = 0; i < 4; ++i)
#pragma unroll
    for (int j = 0; j < 4; ++j)
#pragma unroll
      for (int r = 0; r < 4; ++r) {
        int m = rb + wm * 64 + i * 16 + quad * 4 + r;
        int n = cb + wn * 64 + j * 16 + col;
        out[(size_t)m * DIM + n] = fmaxf(a1[i][j][r], 0.f) + a2[i][j][r];
      }
}

// 256 thr/row, flat grid: zi = blk & (pb-1) -> XCD-partitioned batches.
// Wave0: threshold search (count in [24,48], buffer 64) + append.
// All waves: coalesced fp64 rescore (one candidate row per wave-iteration,
// lane = 8 floats, butterfly reduce). Wave0: 64-lane bitonic -> top-16.
__global__ __launch_bounds__(256) void k_topk(const ushort* __restrict__ simk,
                                              const float* __restrict__ x,
                                              const double* __restrict__ inv64,
                                              int* __restrict__ idx16,
                                              int batch0, int pbm1, int pbsh) {
  int zi = blockIdx.x & pbm1;
  int n = blockIdx.x >> pbsh;
  int batch = batch0 + zi;
  int t = threadIdx.x;
  int wave = t >> 6, lane = t & 63;
  __shared__ int lcnt;
  __shared__ int lidx[64];
  __shared__ double vals[64];
  const ushort* srow = simk + ((size_t)zi * NTOK + (size_t)n) * NTOK;

  // all waves preload their 8 floats of row n (used in every rescore iter)
  const float* xrow = x + ((size_t)batch * NTOK + n) * DIM;
  float4 xa0 = *(const float4*)&xrow[lane * 8];
  float4 xa1 = *(const float4*)&xrow[lane * 8 + 4];
  double dinvn = inv64[(size_t)batch * NTOK + n];

  if (t < 64) {
    if (t == 0) lcnt = 0;  // same-wave LDS program order precedes atomics
    ushort kv[32];
#pragma unroll
    for (int q = 0; q < 4; ++q) {
      ushort8 v8 = *(const ushort8*)&srow[t * 32 + q * 8];
#pragma unroll
      for (int e = 0; e < 8; ++e) kv[q * 8 + e] = v8[e];
    }
    unsigned thr = 0;
    int cnt = NTOK;
    for (int bit = 15; bit >= 0 && cnt > 48; --bit) {
      unsigned cand = thr | (1u << bit);
      int c2 = 0;
#pragma unroll
      for (int j2 = 0; j2 < 32; ++j2) c2 += (kv[j2] >= cand) ? 1 : 0;
#pragma unroll
      for (int off = 1; off < 64; off <<= 1) c2 += __shfl_xor(c2, off);
      if (c2 >= 24) { thr = cand; cnt = c2; }
    }
#pragma unroll
    for (int j2 = 0; j2 < 32; ++j2) {
      if ((unsigned)kv[j2] >= thr) {
        int slot = atomicAdd(&lcnt, 1);
        if (slot < 64) lidx[slot] = t * 32 + j2;
      }
    }
  }
  __syncthreads();
  int c = lcnt < 64 ? lcnt : 64;
  // coalesced rescore: wave w takes slots w, w+4, w+8, ...
  for (int s = wave; s < c; s += 4) {
    int m = lidx[s];
    const float* xc = x + ((size_t)batch * NTOK + m) * DIM;
    float4 b0 = *(const float4*)&xc[lane * 8];
    float4 b1 = *(const float4*)&xc[lane * 8 + 4];
    double sacc = 0.0;
    sacc = fma((double)xa0.x, (double)b0.x, sacc);
    sacc = fma((double)xa0.y, (double)b0.y, sacc);
    sacc = fma((double)xa0.z, (double)b0.z, sacc);
    sacc = fma((double)xa0.w, (double)b0.w, sacc);
    sacc = fma((double)xa1.x, (double)b1.x, sacc);
    sacc = fma((double)xa1.y, (double)b1.y, sacc);
    sacc = fma((double)xa1.z, (double)b1.z, sacc);
    sacc = fma((double)xa1.w, (double)b1.w, sacc);
#pragma unroll
    for (int off = 1; off < 64; off <<= 1) sacc += __shfl_xor(sacc, off);
    if (lane == 0)
      vals[s] = sacc * dinvn * inv64[(size_t)batch * NTOK + m];
  }
  __syncthreads();
  if (t < 64) {
    double sv = (t < c) ? vals[t] : -1.0e300;
    int si = (t < c) ? lidx[t] : 0x7FFFFFFF;
#pragma unroll
    for (int k = 2; k <= 64; k <<= 1) {
#pragma unroll
      for (int jj = k >> 1; jj > 0; jj >>= 1) {
        double ov = __shfl_xor(sv, jj);
        int oi = __shfl_xor(si, jj);
        bool lower = (t & jj) == 0;
        bool desc = (t & k) == 0;
        bool takeFirst = (lower == desc);
        bool otherFirst = (ov > sv) || (ov == sv && oi < si);
        if (takeFirst == otherFirst) { sv = ov; si = oi; }
      }
    }
    if (t < 16) idx16[((size_t)batch * NTOK + n) * 16 + t] = si;
  }
}

// flat grid, batch = blk & 7 (XCD-partitioned). Wave0: mutual + softmax;
// all 128: weighted aggregation of bf16 neighbor rows -> bf16 merged.
__global__ __launch_bounds__(128) void k_merge(const ushort* __restrict__ xb,
                                               const int* __restrict__ idx16,
                                               const float* __restrict__ L,
                                               ushort* __restrict__ mergedb) {
  int b = blockIdx.x & 7;
  int n = blockIdx.x >> 3;
  int row = (b << 11) | n;
  int t = threadIdx.x;
  __shared__ float ps[16];
  __shared__ int ms[16];
  if (t < 64) {
    int k = t & 15;
    int m = idx16[(size_t)row * 16 + k];
    const int* mrow = idx16 + (size_t)(b * NTOK + m) * 16;
    int4 q0 = *(const int4*)&mrow[0];
    int4 q1 = *(const int4*)&mrow[4];
    int4 q2 = *(const int4*)&mrow[8];
    int4 q3 = *(const int4*)&mrow[12];
    bool mut = (q0.x == n) | (q0.y == n) | (q0.z == n) | (q0.w == n) |
               (q1.x == n) | (q1.y == n) | (q1.z == n) | (q1.w == n) |
               (q2.x == n) | (q2.y == n) | (q2.z == n) | (q2.w == n) |
               (q3.x == n) | (q3.y == n) | (q3.z == n) | (q3.w == n);
    float l = mut ? L[(size_t)row * 16 + k] : -__builtin_inff();
    float mx = l;
#pragma unroll
    for (int off = 1; off < 16; off <<= 1) mx = fmaxf(mx, __shfl_xor(mx, off));
    float e = mut ? __expf(l - mx) : 0.0f;
    float den = e;
#pragma unroll
    for (int off = 1; off < 16; off <<= 1) den += __shfl_xor(den, off);
    if (t < 16) { ps[t] = e / den; ms[t] = m; }
  }
  __syncthreads();
  float4 acc = {0.f, 0.f, 0.f, 0.f};
#pragma unroll
  for (int k = 0; k < 16; ++k) {
    float pk = ps[k];
    if (pk != 0.0f) {  // uniform across block
      ushort4 v = *(const ushort4*)&xb[(size_t)(b * NTOK + ms[k]) * DIM + t * 4];
      acc.x = fmaf(pk, b2f(v.x), acc.x);
      acc.y = fmaf(pk, b2f(v.y), acc.y);
      acc.z = fmaf(pk, b2f(v.z), acc.z);
      acc.w = fmaf(pk, b2f(v.w), acc.w);
    }
  }
  ushort4 o = {f2b(acc.x), f2b(acc.y), f2b(acc.z), f2b(acc.w)};
  *(ushort4*)&mergedb[(size_t)row * DIM + t * 4] = o;
}

extern "C" void kernel_launch(void* const* d_in, const int* in_sizes, int n_in,
                              void* d_out, int out_size, void* d_ws,
                              size_t ws_size, hipStream_t stream) {
  const float* x = (const float*)d_in[0];
  const float* attn_w = (const float*)d_in[1];
  const float* attn_b = (const float*)d_in[2];
  const float* w_merged = (const float*)d_in[3];
  const float* w_orig = (const float*)d_in[4];
  float* out = (float*)d_out;

  char* w = (char*)d_ws;
  ushort* xnb = (ushort*)(w);                 // 16,777,216
  ushort* xb = (ushort*)(w + 16777216);       // 16,777,216
  double* inv64 = (double*)(w + 33554432);    //    131,072
  ushort* wmb = (ushort*)(w + 33685504);      //    524,288
  ushort* wob = (ushort*)(w + 34209792);      //    524,288
  int* idx16 = (int*)(w + 34734080);          //  1,048,576
  float* L = (float*)(w + 35782656);          //  1,048,576 (logits)
  ushort* simk = (ushort*)(w + 36831232);     //  pb x 8,388,608 (16-bit keys)
  ushort* mergedb = (ushort*)(w + 36831232);  // alias: simk dead after topk

  size_t fixed = 36831232ull, per = 8388608ull;
  int pb = 1, pbsh = 0;
  if (ws_size >= fixed + 8 * per) { pb = 8; pbsh = 3; }
  else if (ws_size >= fixed + 4 * per) { pb = 4; pbsh = 2; }
  else if (ws_size >= fixed + 2 * per) { pb = 2; pbsh = 1; }

  k_norm<<<16384, 64, 0, stream>>>(x, attn_w, attn_b, xnb, xb, inv64, L);
  k_castw<<<256, 256, 0, stream>>>(w_merged, w_orig, wmb, wob);
  for (int b = 0; b < 8; b += pb) {
    k_simgemm<<<dim3(16, 16, pb), 256, 0, stream>>>(
        xnb + (size_t)b * NTOK * DIM, simk);
    k_topk<<<NTOK * pb, 256, 0, stream>>>(simk, x, inv64, idx16, b, pb - 1,
                                          pbsh);
  }
  k_merge<<<16384, 128, 0, stream>>>(xb, idx16, L, mergedb);
  k_proj<<<dim3(128, 4), 256, 0, stream>>>(mergedb, wmb, xb, wob, out);
}

// Round 8
// 324.614 us; speedup vs baseline: 1.4284x; 1.1030x over previous
//
#include <hip/hip_runtime.h>
#include <math.h>

// Problem: B=8, N=2048, D=512, K=16
// R8: k_topk selection = 2-level radix histogram (per-wave privatized LDS
// hists, all 256 threads) -> exact 16-bit threshold with count in [24,~28];
// coalesced fp64 rescore (R7); 32-lane bitonic -> exact reference order.

#define NTOK 2048
#define DIM 512

typedef __attribute__((ext_vector_type(8))) __bf16 bf16x8;
typedef __attribute__((ext_vector_type(4))) float f32x4;
typedef __attribute__((ext_vector_type(8))) unsigned short ushort8;

#define GLDS(gp, lp)                                                      \
  __builtin_amdgcn_global_load_lds(                                       \
      (const __attribute__((address_space(1))) void*)(gp),                \
      (__attribute__((address_space(3))) void*)(lp), 16, 0, 0)

__device__ __forceinline__ ushort f2b(float f) {  // RNE fp32->bf16
  unsigned u = __float_as_uint(f);
  return (ushort)((u + 0x7fffu + ((u >> 16) & 1u)) >> 16);
}
__device__ __forceinline__ float b2f(ushort h) {
  return __uint_as_float((unsigned)h << 16);
}
__device__ __forceinline__ ushort f2key(float v) {  // fp16 RNE + order map
  union { _Float16 h; ushort u; } cv;
  cv.h = (_Float16)v;
  ushort hb = cv.u;
  return (hb & 0x8000u) ? (ushort)~hb : (ushort)(hb | 0x8000u);
}

// norm: xnb=bf16(x/|x|), xb=bf16(x), inv64=1/|x|, L=x@aw^T+ab (fp32 logits)
__global__ __launch_bounds__(64) void k_norm(const float* __restrict__ x,
                                             const float* __restrict__ aw,
                                             const float* __restrict__ ab,
                                             ushort* __restrict__ xnb,
                                             ushort* __restrict__ xb,
                                             double* __restrict__ inv64,
                                             float* __restrict__ L) {
  int row = blockIdx.x, lane = threadIdx.x;
  const float* xr = x + (size_t)row * DIM;
  float4 a = *(const float4*)&xr[lane * 8];
  float4 b = *(const float4*)&xr[lane * 8 + 4];

  float s[16];
#pragma unroll
  for (int k = 0; k < 16; ++k) {
    const float4 w0 = *(const float4*)&aw[(size_t)k * DIM + lane * 8];
    const float4 w1 = *(const float4*)&aw[(size_t)k * DIM + lane * 8 + 4];
    s[k] = a.x * w0.x + a.y * w0.y + a.z * w0.z + a.w * w0.w + b.x * w1.x +
           b.y * w1.y + b.z * w1.z + b.w * w1.w;
  }
#pragma unroll
  for (int off = 1; off < 64; off <<= 1)
#pragma unroll
    for (int k = 0; k < 16; ++k) s[k] += __shfl_xor(s[k], off);

  double ss = (double)a.x * a.x + (double)a.y * a.y + (double)a.z * a.z +
              (double)a.w * a.w + (double)b.x * b.x + (double)b.y * b.y +
              (double)b.z * b.z + (double)b.w * b.w;
#pragma unroll
  for (int off = 32; off >= 1; off >>= 1) ss += __shfl_xor(ss, off);
  double inv = 1.0 / sqrt(ss);
  if (lane == 0) {
    inv64[row] = inv;
#pragma unroll
    for (int k = 0; k < 16; ++k) L[(size_t)row * 16 + k] = s[k] + ab[k];
  }
  float f = (float)inv;
  size_t o = (size_t)row * DIM + lane * 8;
  ushort4 r0 = {f2b(a.x), f2b(a.y), f2b(a.z), f2b(a.w)};
  ushort4 r1 = {f2b(b.x), f2b(b.y), f2b(b.z), f2b(b.w)};
  *(ushort4*)&xb[o] = r0;
  *(ushort4*)&xb[o + 4] = r1;
  ushort4 n0 = {f2b(a.x * f), f2b(a.y * f), f2b(a.z * f), f2b(a.w * f)};
  ushort4 n1 = {f2b(b.x * f), f2b(b.y * f), f2b(b.z * f), f2b(b.w * f)};
  *(ushort4*)&xnb[o] = n0;
  *(ushort4*)&xnb[o + 4] = n1;
}

__global__ __launch_bounds__(256) void k_castw(const float* __restrict__ a,
                                               const float* __restrict__ b,
                                               ushort* __restrict__ ab,
                                               ushort* __restrict__ bb) {
  int i = (blockIdx.x * 256 + threadIdx.x) * 4;
  float4 va = *(const float4*)&a[i];
  float4 vb = *(const float4*)&b[i];
  ushort4 oa = {f2b(va.x), f2b(va.y), f2b(va.z), f2b(va.w)};
  ushort4 ob = {f2b(vb.x), f2b(vb.y), f2b(vb.z), f2b(vb.w)};
  *(ushort4*)&ab[i] = oa;
  *(ushort4*)&bb[i] = ob;
}

// shared bf16 MFMA K-loop (B^T): C128x128 += A[rb..][k]*B[cb..][k]
__device__ __forceinline__ void bt_kloop(const ushort* __restrict__ A,
                                         const ushort* __restrict__ B,
                                         ushort* lA, ushort* lB, int rb, int cb,
                                         int tid, f32x4 (&acc)[4][4]) {
  int wv = tid >> 6, ln = tid & 63;
  int wm = wv >> 1, wn = wv & 1;
  int col = ln & 15, quad = ln >> 4;
  for (int kt = 0; kt < DIM; kt += 32) {
#pragma unroll
    for (int j = 0; j < 2; ++j) {
      int c = j * 256 + wv * 64 + ln;
      int r = c >> 2, seg = c & 3;
      GLDS(A + (size_t)(rb + r) * DIM + kt + seg * 8, lA + c * 8);
      GLDS(B + (size_t)(cb + r) * DIM + kt + seg * 8, lB + c * 8);
    }
    __syncthreads();
    bf16x8 af[4], bf[4];
#pragma unroll
    for (int i = 0; i < 4; ++i) {
      af[i] = *(const bf16x8*)&lA[(wm * 64 + i * 16 + col) * 32 + quad * 8];
      bf[i] = *(const bf16x8*)&lB[(wn * 64 + i * 16 + col) * 32 + quad * 8];
    }
#pragma unroll
    for (int i = 0; i < 4; ++i)
#pragma unroll
      for (int j = 0; j < 4; ++j)
        acc[i][j] =
            __builtin_amdgcn_mfma_f32_16x16x32_bf16(af[i], bf[j], acc[i][j], 0, 0, 0);
    __syncthreads();
  }
}

// key matrix (16-bit) = map(fp16(Xn_z @ Xn_z^T)), written transposed
__global__ __launch_bounds__(256) void k_simgemm(const ushort* __restrict__ Xn,
                                                 ushort* __restrict__ Skey) {
  __shared__ ushort lA[128 * 32];
  __shared__ ushort lB[128 * 32];
  int tid = threadIdx.x;
  int z = blockIdx.z;
  const ushort* Xb = Xn + (size_t)z * NTOK * DIM;
  ushort* Sb = Skey + (size_t)z * NTOK * NTOK;
  int rb = blockIdx.x * 128, cb = blockIdx.y * 128;
  f32x4 zero = {0.f, 0.f, 0.f, 0.f};
  f32x4 acc[4][4];
#pragma unroll
  for (int i = 0; i < 4; ++i)
#pragma unroll
    for (int j = 0; j < 4; ++j) acc[i][j] = zero;
  bt_kloop(Xb, Xb, lA, lB, rb, cb, tid, acc);
  int wv = tid >> 6, ln = tid & 63;
  int wm = wv >> 1, wn = wv & 1;
  int col = ln & 15, quad = ln >> 4;
#pragma unroll
  for (int i = 0; i < 4; ++i)
#pragma unroll
    for (int j = 0; j < 4; ++j) {
      int m0 = rb + wm * 64 + i * 16 + quad * 4;
      int nn = cb + wn * 64 + j * 16 + col;
      ushort4 kk = {f2key(acc[i][j][0]), f2key(acc[i][j][1]),
                    f2key(acc[i][j][2]), f2key(acc[i][j][3])};
      *(ushort4*)&Sb[(size_t)nn * NTOK + m0] = kk;  // W symmetric
    }
}

// out = relu(Mg@Wm^T) + Xg@Wo^T
__global__ __launch_bounds__(256) void k_proj(const ushort* __restrict__ Mg,
                                              const ushort* __restrict__ Wm,
                                              const ushort* __restrict__ Xg,
                                              const ushort* __restrict__ Wo,
                                              float* __restrict__ out) {
  __shared__ ushort lA[128 * 32];
  __shared__ ushort lB[128 * 32];
  int tid = threadIdx.x;
  int rb = blockIdx.x * 128, cb = blockIdx.y * 128;
  f32x4 zero = {0.f, 0.f, 0.f, 0.f};
  f32x4 a1[4][4], a2[4][4];
#pragma unroll
  for (int i = 0; i < 4; ++i)
#pragma unroll
    for (int j = 0; j < 4; ++j) { a1[i][j] = zero; a2[i][j] = zero; }
  bt_kloop(Mg, Wm, lA, lB, rb, cb, tid, a1);
  bt_kloop(Xg, Wo, lA, lB, rb, cb, tid, a2);
  int wv = tid >> 6, ln = tid & 63;
  int wm = wv >> 1, wn = wv & 1;
  int col = ln & 15, quad = ln >> 4;
#pragma unroll
  for (int i = 0; i < 4; ++i)
#pragma unroll
    for (int j = 0; j < 4; ++j)
#pragma unroll
      for (int r = 0; r < 4; ++r) {
        int m = rb + wm * 64 + i * 16 + quad * 4 + r;
        int n = cb + wn * 64 + j * 16 + col;
        out[(size_t)m * DIM + n] = fmaxf(a1[i][j][r], 0.f) + a2[i][j][r];
      }
}

#define TARGET 24

// suffix-scan of a merged 256-bucket histogram on wave0; returns (via LDS)
// the largest bucket v with suffix-count >= tgt, and suffix-count(v+1).
__device__ __forceinline__ void scan_pick(const unsigned* hist, int lane,
                                          int tgt, int* out_v,
                                          unsigned* out_cntv1) {
  int base = lane * 4;
  unsigned h0 = hist[0 * 256 + base + 0] + hist[1 * 256 + base + 0] +
                hist[2 * 256 + base + 0] + hist[3 * 256 + base + 0];
  unsigned h1 = hist[0 * 256 + base + 1] + hist[1 * 256 + base + 1] +
                hist[2 * 256 + base + 1] + hist[3 * 256 + base + 1];
  unsigned h2 = hist[0 * 256 + base + 2] + hist[1 * 256 + base + 2] +
                hist[2 * 256 + base + 2] + hist[3 * 256 + base + 2];
  unsigned h3 = hist[0 * 256 + base + 3] + hist[1 * 256 + base + 3] +
                hist[2 * 256 + base + 3] + hist[3 * 256 + base + 3];
  unsigned s3 = h3, s2 = h2 + s3, s1 = h1 + s2, s0 = h0 + s1;
  unsigned inc = s0;
#pragma unroll
  for (int off = 1; off < 64; off <<= 1) {
    unsigned o = __shfl_down(inc, off);
    if (lane + off < 64) inc += o;
  }
  unsigned above = inc - s0;  // sum over buckets >= 4*(lane+1)
  int vb = -1;
  if (above + s0 >= (unsigned)tgt) vb = base + 0;
  if (above + s1 >= (unsigned)tgt) vb = base + 1;
  if (above + s2 >= (unsigned)tgt) vb = base + 2;
  if (above + s3 >= (unsigned)tgt) vb = base + 3;
  int v = vb;
#pragma unroll
  for (int off = 1; off < 64; off <<= 1) v = max(v, __shfl_xor(v, off));
  unsigned v1 = 0;
  if ((v >> 2) == lane) {
    int k = v & 3;
    v1 = (k == 0) ? above + s1 : (k == 1) ? above + s2
                               : (k == 2) ? above + s3 : above;
  }
  v1 = __shfl(v1, v >> 2);
  *out_v = v;
  *out_cntv1 = v1;
}

// 256 thr/row, flat grid: zi = blk & (pb-1) -> XCD-partitioned batches.
// Selection: 2-level radix histogram -> exact 16-bit threshold, count in
// [24, 24+dups] (cap 32, safe: 16-rank margin). Rescore: coalesced fp64,
// one candidate/wave-iter. Wave0: 32-lane bitonic -> top-16 ref order.
__global__ __launch_bounds__(256) void k_topk(const ushort* __restrict__ simk,
                                              const float* __restrict__ x,
                                              const double* __restrict__ inv64,
                                              int* __restrict__ idx16,
                                              int batch0, int pbm1, int pbsh) {
  int zi = blockIdx.x & pbm1;
  int n = blockIdx.x >> pbsh;
  int batch = batch0 + zi;
  int t = threadIdx.x;
  int wave = t >> 6, lane = t & 63;
  __shared__ unsigned hist[4 * 256];
  __shared__ int lidx[32];
  __shared__ double vals[32];
  __shared__ int shv, sneed, sthr, lcnt;
  const ushort* srow = simk + ((size_t)zi * NTOK + (size_t)n) * NTOK;

  // preload this row's fragment (reused every rescore iteration)
  const float* xrow = x + ((size_t)batch * NTOK + n) * DIM;
  float4 xa0 = *(const float4*)&xrow[lane * 8];
  float4 xa1 = *(const float4*)&xrow[lane * 8 + 4];
  double dinvn = inv64[(size_t)batch * NTOK + n];

  // load 8 keys/thread
  ushort kv[8];
  {
    ushort8 v8 = *(const ushort8*)&srow[t * 8];
#pragma unroll
    for (int e = 0; e < 8; ++e) kv[e] = v8[e];
  }
  // zero histograms
#pragma unroll
  for (int i = 0; i < 4; ++i) hist[t + 256 * i] = 0;
  if (t == 0) lcnt = 0;
  __syncthreads();
  // pass 1: high byte
#pragma unroll
  for (int j = 0; j < 8; ++j)
    atomicAdd(&hist[wave * 256 + (kv[j] >> 8)], 1u);
  __syncthreads();
  if (wave == 0) {
    int v;
    unsigned v1;
    scan_pick(hist, lane, TARGET, &v, &v1);
    if (lane == 0) { shv = v; sneed = TARGET - (int)v1; }
  }
  __syncthreads();
  int v = shv;
  // pass 2: low byte within boundary bucket
#pragma unroll
  for (int i = 0; i < 4; ++i) hist[t + 256 * i] = 0;
  __syncthreads();
#pragma unroll
  for (int j = 0; j < 8; ++j)
    if ((kv[j] >> 8) == v) atomicAdd(&hist[wave * 256 + (kv[j] & 255)], 1u);
  __syncthreads();
  if (wave == 0) {
    int u;
    unsigned dummy;
    scan_pick(hist, lane, sneed, &u, &dummy);
    if (lane == 0) sthr = (v << 8) | u;
  }
  __syncthreads();
  unsigned thr = (unsigned)sthr;
  // compaction
#pragma unroll
  for (int j = 0; j < 8; ++j) {
    if ((unsigned)kv[j] >= thr) {
      int slot = atomicAdd(&lcnt, 1);
      if (slot < 32) lidx[slot] = t * 8 + j;
    }
  }
  __syncthreads();
  int c = lcnt < 32 ? lcnt : 32;
  // coalesced fp64 rescore: wave w takes slots w, w+4, ...
  for (int s = wave; s < c; s += 4) {
    int m = lidx[s];
    const float* xc = x + ((size_t)batch * NTOK + m) * DIM;
    float4 b0 = *(const float4*)&xc[lane * 8];
    float4 b1 = *(const float4*)&xc[lane * 8 + 4];
    double sacc = 0.0;
    sacc = fma((double)xa0.x, (double)b0.x, sacc);
    sacc = fma((double)xa0.y, (double)b0.y, sacc);
    sacc = fma((double)xa0.z, (double)b0.z, sacc);
    sacc = fma((double)xa0.w, (double)b0.w, sacc);
    sacc = fma((double)xa1.x, (double)b1.x, sacc);
    sacc = fma((double)xa1.y, (double)b1.y, sacc);
    sacc = fma((double)xa1.z, (double)b1.z, sacc);
    sacc = fma((double)xa1.w, (double)b1.w, sacc);
#pragma unroll
    for (int off = 1; off < 64; off <<= 1) sacc += __shfl_xor(sacc, off);
    if (lane == 0)
      vals[s] = sacc * dinvn * inv64[(size_t)batch * NTOK + m];
  }
  __syncthreads();
  if (t < 32) {
    double sv = (t < c) ? vals[t] : -1.0e300;
    int si = (t < c) ? lidx[t] : 0x7FFFFFFF;
#pragma unroll
    for (int k = 2; k <= 32; k <<= 1) {
#pragma unroll
      for (int jj = k >> 1; jj > 0; jj >>= 1) {
        double ov = __shfl_xor(sv, jj);
        int oi = __shfl_xor(si, jj);
        bool lower = (t & jj) == 0;
        bool desc = (t & k) == 0;
        bool takeFirst = (lower == desc);
        bool otherFirst = (ov > sv) || (ov == sv && oi < si);
        if (takeFirst == otherFirst) { sv = ov; si = oi; }
      }
    }
    if (t < 16) idx16[((size_t)batch * NTOK + n) * 16 + t] = si;
  }
}

// flat grid, batch = blk & 7 (XCD-partitioned). Wave0: mutual + softmax;
// all 128: weighted aggregation of bf16 neighbor rows -> bf16 merged.
__global__ __launch_bounds__(128) void k_merge(const ushort* __restrict__ xb,
                                               const int* __restrict__ idx16,
                                               const float* __restrict__ L,
                                               ushort* __restrict__ mergedb) {
  int b = blockIdx.x & 7;
  int n = blockIdx.x >> 3;
  int row = (b << 11) | n;
  int t = threadIdx.x;
  __shared__ float ps[16];
  __shared__ int ms[16];
  if (t < 64) {
    int k = t & 15;
    int m = idx16[(size_t)row * 16 + k];
    const int* mrow = idx16 + (size_t)(b * NTOK + m) * 16;
    int4 q0 = *(const int4*)&mrow[0];
    int4 q1 = *(const int4*)&mrow[4];
    int4 q2 = *(const int4*)&mrow[8];
    int4 q3 = *(const int4*)&mrow[12];
    bool mut = (q0.x == n) | (q0.y == n) | (q0.z == n) | (q0.w == n) |
               (q1.x == n) | (q1.y == n) | (q1.z == n) | (q1.w == n) |
               (q2.x == n) | (q2.y == n) | (q2.z == n) | (q2.w == n) |
               (q3.x == n) | (q3.y == n) | (q3.z == n) | (q3.w == n);
    float l = mut ? L[(size_t)row * 16 + k] : -__builtin_inff();
    float mx = l;
#pragma unroll
    for (int off = 1; off < 16; off <<= 1) mx = fmaxf(mx, __shfl_xor(mx, off));
    float e = mut ? __expf(l - mx) : 0.0f;
    float den = e;
#pragma unroll
    for (int off = 1; off < 16; off <<= 1) den += __shfl_xor(den, off);
    if (t < 16) { ps[t] = e / den; ms[t] = m; }
  }
  __syncthreads();
  float4 acc = {0.f, 0.f, 0.f, 0.f};
#pragma unroll
  for (int k = 0; k < 16; ++k) {
    float pk = ps[k];
    if (pk != 0.0f) {  // uniform across block
      ushort4 v = *(const ushort4*)&xb[(size_t)(b * NTOK + ms[k]) * DIM + t * 4];
      acc.x = fmaf(pk, b2f(v.x), acc.x);
      acc.y = fmaf(pk, b2f(v.y), acc.y);
      acc.z = fmaf(pk, b2f(v.z), acc.z);
      acc.w = fmaf(pk, b2f(v.w), acc.w);
    }
  }
  ushort4 o = {f2b(acc.x), f2b(acc.y), f2b(acc.z), f2b(acc.w)};
  *(ushort4*)&mergedb[(size_t)row * DIM + t * 4] = o;
}

extern "C" void kernel_launch(void* const* d_in, const int* in_sizes, int n_in,
                              void* d_out, int out_size, void* d_ws,
                              size_t ws_size, hipStream_t stream) {
  const float* x = (const float*)d_in[0];
  const float* attn_w = (const float*)d_in[1];
  const float* attn_b = (const float*)d_in[2];
  const float* w_merged = (const float*)d_in[3];
  const float* w_orig = (const float*)d_in[4];
  float* out = (float*)d_out;

  char* w = (char*)d_ws;
  ushort* xnb = (ushort*)(w);                 // 16,777,216
  ushort* xb = (ushort*)(w + 16777216);       // 16,777,216
  double* inv64 = (double*)(w + 33554432);    //    131,072
  ushort* wmb = (ushort*)(w + 33685504);      //    524,288
  ushort* wob = (ushort*)(w + 34209792);      //    524,288
  int* idx16 = (int*)(w + 34734080);          //  1,048,576
  float* L = (float*)(w + 35782656);          //  1,048,576 (logits)
  ushort* simk = (ushort*)(w + 36831232);     //  pb x 8,388,608 (16-bit keys)
  ushort* mergedb = (ushort*)(w + 36831232);  // alias: simk dead after topk

  size_t fixed = 36831232ull, per = 8388608ull;
  int pb = 1, pbsh = 0;
  if (ws_size >= fixed + 8 * per) { pb = 8; pbsh = 3; }
  else if (ws_size >= fixed + 4 * per) { pb = 4; pbsh = 2; }
  else if (ws_size >= fixed + 2 * per) { pb = 2; pbsh = 1; }

  k_norm<<<16384, 64, 0, stream>>>(x, attn_w, attn_b, xnb, xb, inv64, L);
  k_castw<<<256, 256, 0, stream>>>(w_merged, w_orig, wmb, wob);
  for (int b = 0; b < 8; b += pb) {
    k_simgemm<<<dim3(16, 16, pb), 256, 0, stream>>>(
        xnb + (size_t)b * NTOK * DIM, simk);
    k_topk<<<NTOK * pb, 256, 0, stream>>>(simk, x, inv64, idx16, b, pb - 1,
                                          pbsh);
  }
  k_merge<<<16384, 128, 0, stream>>>(xb, idx16, L, mergedb);
  k_proj<<<dim3(128, 4), 256, 0, stream>>>(mergedb, wmb, xb, wob, out);
}